// Round 1
// baseline (169.383 us; speedup 1.0000x reference)
//
#include <hip/hip_runtime.h>

#define NS 65536
#define DD 32
#define RR 128

// Precompute: SW[r][d] = sqrt(log2(e)/2) / clamp(b,1e-8)  (so exponent accumulates in log2 domain)
//             CK[r][d] = c[r][d] (repacked to 16B-aligned stride-32 rows), BIAS[r] = c[r][32]
__global__ void anfis_pre(const float* __restrict__ b, const float* __restrict__ c,
                          float* __restrict__ SW, float* __restrict__ CK,
                          float* __restrict__ BIAS) {
    int i = blockIdx.x * 256 + threadIdx.x;
    if (i < RR * DD) {
        float bc = fmaxf(b[i], 1e-8f);
        SW[i] = 0.8493218003f / bc;      // sqrt(0.5 * log2(e))
        int r = i >> 5, d = i & 31;
        CK[i] = c[r * 33 + d];
        if (d == 0) BIAS[r] = c[r * 33 + 32];
    }
}

// Block = 256 threads = 4 waves. Block covers 64 samples; wave w covers rules [32w, 32w+32).
// lane = sample. Strengths staged in per-wave LDS tile [64][33] (odd stride -> conflict-free),
// flushed with lane-contiguous float4 stores. Cross-wave ssum/dot via LDS partials.
__global__ __launch_bounds__(256, 4) void anfis_main(
    const float* __restrict__ X, const float* __restrict__ A,
    const float* __restrict__ SW, const float* __restrict__ CK,
    const float* __restrict__ BIAS,
    float* __restrict__ out_pred, float* __restrict__ out_str,
    float* __restrict__ out_norm)
{
    __shared__ float SBUF[4][64 * 33];   // 33792 B
    __shared__ float pS[4][64];
    __shared__ float pD[4][64];
    __shared__ float scale_lds[64];

    const int tid  = threadIdx.x;
    const int w    = tid >> 6;           // wave = rule quarter
    const int lane = tid & 63;           // lane = sample within block
    const int n    = blockIdx.x * 64 + lane;

    // Load this sample's x row (128 B, float4-vectorized; shared across the 4 waves via L1)
    float x[DD];
    {
        const float4* Xv = reinterpret_cast<const float4*>(X + (size_t)n * DD);
        #pragma unroll
        for (int i = 0; i < DD / 4; ++i) {
            float4 v = Xv[i];
            x[4*i+0] = v.x; x[4*i+1] = v.y; x[4*i+2] = v.z; x[4*i+3] = v.w;
        }
    }

    float ssum = 0.0f, dot = 0.0f;
    const int r0 = w * 32;
    for (int i = 0; i < 32; ++i) {
        const int r = r0 + i;
        const float* ar = A  + r * DD;   // wave-uniform addresses -> L1 broadcast loads
        const float* sr = SW + r * DD;
        const float* cr = CK + r * DD;
        float s  = 0.0f;
        float ro = BIAS[r];
        #pragma unroll
        for (int d = 0; d < DD; ++d) {
            float diff = x[d] - ar[d];       // diff-form: safe vs. catastrophic cancellation
            float t    = diff * sr[d];       // t^2 = log2e * (x-a)^2 / (2 b^2)
            s  = fmaf(t, t, s);
            ro = fmaf(x[d], cr[d], ro);      // consequent: X @ c^T (+bias)
        }
        float st = __builtin_amdgcn_exp2f(-s);   // strength = 2^(-s) = exp(-sum (x-a)^2/(2b^2))
        SBUF[w][lane * 33 + i] = st;             // bank = (lane+i)%32 -> 2-way, free
        ssum += st;
        dot = fmaf(st, ro, dot);
    }
    pS[w][lane] = ssum;
    pD[w][lane] = dot;
    __syncthreads();

    // Finalize scale & predictions (wave 0), concurrent with strengths flush on all waves
    if (w == 0) {
        float ss = pS[0][lane] + pS[1][lane] + pS[2][lane] + pS[3][lane];
        float dd = pD[0][lane] + pD[1][lane] + pD[2][lane] + pD[3][lane];
        float sc = 1.0f / (ss + 1e-8f);
        out_pred[n]     = dd * sc;
        scale_lds[lane] = sc;
    }

    // Strengths flush: per instr 64 lanes cover 8 sample-rows x 32 B... (8 x 128 B full segments)
    const int a8 = lane >> 3;   // row-in-group 0..7
    const int k8 = lane & 7;    // float4 index within the 32-col quarter
    #pragma unroll
    for (int it = 0; it < 8; ++it) {
        int si = it * 8 + a8;
        const float* row = &SBUF[w][si * 33 + k8 * 4];
        float4 v = make_float4(row[0], row[1], row[2], row[3]);
        float4* dst = reinterpret_cast<float4*>(
            out_str + (size_t)(blockIdx.x * 64 + si) * RR + w * 32) + k8;
        *dst = v;
    }
    __syncthreads();

    // Normalized flush: same LDS tile x scale (no global round-trip)
    #pragma unroll
    for (int it = 0; it < 8; ++it) {
        int si = it * 8 + a8;
        float sc = scale_lds[si];
        const float* row = &SBUF[w][si * 33 + k8 * 4];
        float4 v = make_float4(row[0] * sc, row[1] * sc, row[2] * sc, row[3] * sc);
        float4* dst = reinterpret_cast<float4*>(
            out_norm + (size_t)(blockIdx.x * 64 + si) * RR + w * 32) + k8;
        *dst = v;
    }
}

extern "C" void kernel_launch(void* const* d_in, const int* in_sizes, int n_in,
                              void* d_out, int out_size, void* d_ws, size_t ws_size,
                              hipStream_t stream) {
    const float* X = (const float*)d_in[0];
    const float* A = (const float*)d_in[1];
    const float* B = (const float*)d_in[2];
    const float* C = (const float*)d_in[3];

    float* SW   = (float*)d_ws;          // 4096 floats
    float* CK   = SW + RR * DD;          // 4096 floats
    float* BIAS = CK + RR * DD;          // 128 floats

    float* pred = (float*)d_out;
    float* str  = pred + NS;
    float* nrm  = str + (size_t)NS * RR;

    anfis_pre<<<dim3((RR * DD + 255) / 256), dim3(256), 0, stream>>>(B, C, SW, CK, BIAS);
    anfis_main<<<dim3(NS / 64), dim3(256), 0, stream>>>(X, A, SW, CK, BIAS, pred, str, nrm);
}

// Round 2
// 132.792 us; speedup vs baseline: 1.2756x; 1.2756x over previous
//
#include <hip/hip_runtime.h>

#define NS 65536
#define DD 32
#define RR 128

// 64-lane sum reduction: 5 ds_swizzle steps within 32-lane halves, then one
// cross-half shfl_xor(32). All lanes end with the full sum.
__device__ inline float wave64_sum(float v) {
    v += __int_as_float(__builtin_amdgcn_ds_swizzle(__float_as_int(v), 0x041F)); // ^1
    v += __int_as_float(__builtin_amdgcn_ds_swizzle(__float_as_int(v), 0x081F)); // ^2
    v += __int_as_float(__builtin_amdgcn_ds_swizzle(__float_as_int(v), 0x101F)); // ^4
    v += __int_as_float(__builtin_amdgcn_ds_swizzle(__float_as_int(v), 0x201F)); // ^8
    v += __int_as_float(__builtin_amdgcn_ds_swizzle(__float_as_int(v), 0x401F)); // ^16
    v += __shfl_xor(v, 32);                                                      // ^32
    return v;
}

// Block = 256 threads = 4 waves = 2 wave-pairs. lane = RULE (pair covers 128 rules),
// each pair handles 32 samples; block covers 64 samples. Rule params live in VGPRs
// (loaded once), X rows are wave-uniform loads (double-buffered), so the sample loop
// is a pure-VALU 128-op body + exp2 + cross-lane reduction.
__global__ __launch_bounds__(256, 2) void anfis_main(
    const float* __restrict__ X, const float* __restrict__ A,
    const float* __restrict__ B, const float* __restrict__ C,
    float* __restrict__ out_pred, float* __restrict__ out_str,
    float* __restrict__ out_norm)
{
    __shared__ float SBUF[64 * RR];      // 32 KB strengths staging, row = sample-in-block
    __shared__ float pS[4][32];          // per-wave per-sample strength partial sums
    __shared__ float pD[4][32];          // per-wave per-sample dot partial sums
    __shared__ float scale_lds[64];

    const int tid  = threadIdx.x;
    const int w    = tid >> 6;                 // wave id 0..3
    const int lane = tid & 63;
    const int r    = ((w & 1) << 6) | lane;    // rule id: pair covers 0..127
    const int pair = w >> 1;                   // sample-group within block
    const int sbase = pair * 32;               // sample-in-block base
    const int nbase = blockIdx.x * 64 + sbase;

    // ---- per-thread rule params, held in registers for the whole kernel ----
    float a_[DD], sw_[DD], ck_[DD], bias;
    {
        const float4* av = (const float4*)(A + r * DD);
        const float4* bv = (const float4*)(B + r * DD);
        #pragma unroll
        for (int i = 0; i < 8; ++i) {
            float4 va = av[i];
            a_[4*i+0] = va.x; a_[4*i+1] = va.y; a_[4*i+2] = va.z; a_[4*i+3] = va.w;
            float4 vb = bv[i];
            // sw = sqrt(log2(e)/2) / clamp(b,1e-8): exponent accumulates in log2 domain
            sw_[4*i+0] = 0.8493218003f * __builtin_amdgcn_rcpf(fmaxf(vb.x, 1e-8f));
            sw_[4*i+1] = 0.8493218003f * __builtin_amdgcn_rcpf(fmaxf(vb.y, 1e-8f));
            sw_[4*i+2] = 0.8493218003f * __builtin_amdgcn_rcpf(fmaxf(vb.z, 1e-8f));
            sw_[4*i+3] = 0.8493218003f * __builtin_amdgcn_rcpf(fmaxf(vb.w, 1e-8f));
        }
        #pragma unroll
        for (int d = 0; d < DD; ++d) ck_[d] = C[r * (DD + 1) + d];
        bias = C[r * (DD + 1) + DD];
    }

    // ---- sample loop: double-buffered wave-uniform X rows ----
    float xA[DD], xB[DD];
    auto loadx = [&](float* xs, int j) {
        const float4* xp = (const float4*)(X + (size_t)(nbase + j) * DD);
        #pragma unroll
        for (int i = 0; i < 8; ++i) {
            float4 v = xp[i];
            xs[4*i+0] = v.x; xs[4*i+1] = v.y; xs[4*i+2] = v.z; xs[4*i+3] = v.w;
        }
    };
    auto compute = [&](const float* xs, int j) {
        float s0 = 0.f, s1 = 0.f, ro0 = bias, ro1 = 0.f;   // 2 chains each: ILP
        #pragma unroll
        for (int d = 0; d < DD; d += 2) {
            float d0 = xs[d]     - a_[d];     float t0 = d0 * sw_[d];     s0 = fmaf(t0, t0, s0);
            float d1 = xs[d + 1] - a_[d + 1]; float t1 = d1 * sw_[d + 1]; s1 = fmaf(t1, t1, s1);
            ro0 = fmaf(xs[d],     ck_[d],     ro0);
            ro1 = fmaf(xs[d + 1], ck_[d + 1], ro1);
        }
        float st = __builtin_amdgcn_exp2f(-(s0 + s1));  // strength
        float ro = ro0 + ro1;                            // rule_out
        SBUF[(sbase + j) * RR + r] = st;                 // stride-1 dwords: 2-way bank = free
        float fs = wave64_sum(st);
        float fd = wave64_sum(st * ro);
        if (lane == 0) { pS[w][j] = fs; pD[w][j] = fd; }
    };

    loadx(xA, 0);
    for (int j = 0; j < 32; j += 2) {
        loadx(xB, j + 1);            // prefetch while computing j
        compute(xA, j);
        if (j + 2 < 32) loadx(xA, j + 2);
        compute(xB, j + 1);
    }
    __syncthreads();

    // ---- scale + predictions (wave 0; sample-in-block == tid for tid<64) ----
    if (tid < 64) {
        int p = tid >> 5, j2 = tid & 31;
        float ss = pS[2 * p][j2] + pS[2 * p + 1][j2];
        float dd = pD[2 * p][j2] + pD[2 * p + 1][j2];
        float sc = 1.0f / (ss + 1e-8f);
        out_pred[blockIdx.x * 64 + tid] = dd * sc;
        scale_lds[tid] = sc;
    }
    __syncthreads();

    // ---- flush strengths + normalized from LDS, float4-coalesced ----
    #pragma unroll
    for (int it = 0; it < 8; ++it) {
        int f   = it * 256 + tid;        // float4 index over 64x32 tile
        int row = f >> 5;                // sample-in-block
        int col = f & 31;                // float4 column
        float4 v = *(const float4*)&SBUF[row * RR + col * 4];
        float sc = scale_lds[row];
        size_t base = ((size_t)(blockIdx.x * 64 + row)) * RR + col * 4;
        *(float4*)(out_str + base) = v;
        *(float4*)(out_norm + base) = make_float4(v.x * sc, v.y * sc, v.z * sc, v.w * sc);
    }
}

extern "C" void kernel_launch(void* const* d_in, const int* in_sizes, int n_in,
                              void* d_out, int out_size, void* d_ws, size_t ws_size,
                              hipStream_t stream) {
    const float* X = (const float*)d_in[0];
    const float* A = (const float*)d_in[1];
    const float* B = (const float*)d_in[2];
    const float* C = (const float*)d_in[3];

    float* pred = (float*)d_out;
    float* str  = pred + NS;
    float* nrm  = str + (size_t)NS * RR;

    anfis_main<<<dim3(NS / 64), dim3(256), 0, stream>>>(X, A, B, C, pred, str, nrm);
}